// Round 5
// baseline (188.938 us; speedup 1.0000x reference)
//
#include <hip/hip_runtime.h>

// Problem constants (fixed by the reference): B=16 lists, N=1024, D=256.
#define BL 16
#define NL 1024
#define DD 256

typedef short bf16x8 __attribute__((ext_vector_type(8)));
typedef float f32x4 __attribute__((ext_vector_type(4)));

static __device__ __forceinline__ short f32_to_bf16(float f) {
  union { float f; unsigned u; } v; v.f = f;
  unsigned r = (v.u + 0x7FFFu + ((v.u >> 16) & 1u)) >> 16;  // RNE
  return (short)r;
}

// FRAGMENT-TILED LAYOUT for all bf16 operands (rows x 256 k):
//   off(row,k) = (row>>4)*4096 + (k>>5)*512 + (((k>>3)&3)*16 + (row&15))*8 + (k&7)
// A wave's MFMA fragment (16 rows x 32 k panel) is then 64 lanes x 16B
// CONTIGUOUS: lane l (row=l&15, quad=l>>4) reads at base + l*8 shorts.
// -> frag loads are single coalesced global_load_dwordx4; no LDS, no barriers.

// Load 4 fragments (4 row-strips of a 64-row tile) at panel p.
static __device__ __forceinline__ void load4(const short* __restrict__ base,
                                             int p, int l, bf16x8 f[4]) {
#pragma unroll
  for (int i = 0; i < 4; ++i)
    f[i] = *(const bf16x8*)(base + i * 4096 + p * 512 + l * 8);
}

// 64x64x256 register GEMM, 2-deep software pipeline, no barriers.
static __device__ __forceinline__ void gemm64(const short* __restrict__ Ab,
                                              const short* __restrict__ Bb,
                                              int l, f32x4 acc[4][4]) {
  bf16x8 a[2][4], b[2][4];
  load4(Ab, 0, l, a[0]);
  load4(Bb, 0, l, b[0]);
#pragma unroll
  for (int p = 0; p < 8; ++p) {
    if (p + 1 < 8) {
      load4(Ab, p + 1, l, a[(p + 1) & 1]);
      load4(Bb, p + 1, l, b[(p + 1) & 1]);
    }
#pragma unroll
    for (int mt = 0; mt < 4; ++mt)
#pragma unroll
      for (int nt = 0; nt < 4; ++nt)
        acc[mt][nt] = __builtin_amdgcn_mfma_f32_16x16x32_bf16(
            a[p & 1][mt], b[p & 1][nt], acc[mt][nt], 0, 0, 0);
  }
}

// ---- Kernel 1: prep. Converts X fp32->bf16 into frag-tiled Xf, and both W
// into frag-tiled (transposed) WTf. One 16B output chunk per thread.
__global__ __launch_bounds__(256) void k_prep(const float* __restrict__ X,
                                              const float* __restrict__ Wu,
                                              const float* __restrict__ Wl,
                                              short* __restrict__ Xf,
                                              short* __restrict__ WTu,
                                              short* __restrict__ WTl) {
  const int tid = blockIdx.x * 256 + threadIdx.x;
  if (tid < BL * NL * 32) {             // 524288 X chunks
    const int strip = tid >> 9, rest = tid & 511;
    const int p = rest >> 6, l = rest & 63;
    const int row = strip * 16 + (l & 15), k0 = p * 32 + (l >> 4) * 8;
    const float4* src = (const float4*)(X + (size_t)row * DD + k0);
    const float4 v0 = src[0], v1 = src[1];
    short o[8] = {f32_to_bf16(v0.x), f32_to_bf16(v0.y), f32_to_bf16(v0.z), f32_to_bf16(v0.w),
                  f32_to_bf16(v1.x), f32_to_bf16(v1.y), f32_to_bf16(v1.z), f32_to_bf16(v1.w)};
    *(bf16x8*)(Xf + (size_t)strip * 4096 + p * 512 + l * 8) = *(bf16x8*)o;
  } else {                              // 16384 W chunks (2 matrices)
    const int g = tid - BL * NL * 32;
    const int z = g >> 13, rest = g & 8191;
    const int strip = rest >> 9, rest2 = rest & 511;
    const int p = rest2 >> 6, l = rest2 & 63;
    const int e = strip * 16 + (l & 15), d0 = p * 32 + (l >> 4) * 8;
    const float* W = z ? Wl : Wu;
    short* WT = z ? WTl : WTu;
    short o[8];
#pragma unroll
    for (int j = 0; j < 8; ++j) o[j] = f32_to_bf16(W[(size_t)(d0 + j) * DD + e]);
    *(bf16x8*)(WT + (size_t)strip * 4096 + p * 512 + l * 8) = *(bf16x8*)o;
  }
}

// ---- Kernel 2: stage 1  Y = Xb * W  (Y[m][nk] = sum_k Xf[m][k]*WT[nk][k]).
// Block = 4 waves = 4 n-tiles (N=256 exactly); blockIdx.x = m-tile of 64.
// Output Y written in frag-tiled layout for stage 2's A-operand.
__global__ __launch_bounds__(256) void k_stage1(const short* __restrict__ Xf,
                                                const short* __restrict__ WTu,
                                                const short* __restrict__ WTl,
                                                short* __restrict__ YU,
                                                short* __restrict__ YL) {
  const int w = threadIdx.x >> 6, l = threadIdx.x & 63;
  const int quad = l >> 4, rcol = l & 15;
  const short* WT = blockIdx.y ? WTl : WTu;
  short* Y = blockIdx.y ? YL : YU;
  const short* Ab = Xf + (size_t)blockIdx.x * 4 * 4096;
  const short* Bb = WT + (size_t)w * 4 * 4096;
  f32x4 acc[4][4] = {};
  gemm64(Ab, Bb, l, acc);
#pragma unroll
  for (int mt = 0; mt < 4; ++mt)
#pragma unroll
    for (int nt = 0; nt < 4; ++nt) {
      const int nk = w * 64 + nt * 16 + rcol;
      short* base = Y + (size_t)(blockIdx.x * 4 + mt) * 4096 + (nk >> 5) * 512 +
                    ((nk >> 3) & 3) * 128 + (nk & 7);
#pragma unroll
      for (int i = 0; i < 4; ++i)
        base[(quad * 4 + i) * 8] = f32_to_bf16(acc[mt][nt][i]);
    }
}

// ---- Kernel 3: stage 2  adj[b][p][q] = Ysel[p]·Xb[q] + bias.
// Block = 4 waves = 4 p-tiles (same q-tile -> B-frags shared via L1).
// No LDS, no barriers. Diagonal wave-tiles: sequential U then L pass.
__global__ __launch_bounds__(256) void k_stage2(const short* __restrict__ Xf,
                                                const short* __restrict__ YU,
                                                const short* __restrict__ YL,
                                                const float* __restrict__ bu_p,
                                                const float* __restrict__ bl_p,
                                                float* __restrict__ out) {
  const int w = threadIdx.x >> 6, l = threadIdx.x & 63;
  const int quad = l >> 4, rcol = l & 15;
  const int qt = blockIdx.x & 15, pb = blockIdx.x >> 4;
  const int b = blockIdx.y;
  const int pti = pb * 4 + w;                 // p-tile 0..15
  const size_t loff = (size_t)b * NL * DD;    // per-list offset (shorts)
  const short* Bb = Xf + loff + (size_t)qt * 4 * 4096;
  float* Ob = out + (size_t)b * NL * NL;
  const int p0 = pti * 64, q0 = qt * 64;
  const float bu = bu_p[0], bl = bl_p[0];
  const bool diag = (pti == qt);
  const int npass = diag ? 2 : 1;

  for (int pass = 0; pass < npass; ++pass) {
    const bool useU = diag ? (pass == 0) : (qt > pti);
    const float bias = useU ? bu : bl;
    const short* Ab = (useU ? YU : YL) + loff + (size_t)pti * 4 * 4096;
    const f32x4 binit = {bias, bias, bias, bias};
    f32x4 acc[4][4];
#pragma unroll
    for (int mt = 0; mt < 4; ++mt)
#pragma unroll
      for (int nt = 0; nt < 4; ++nt) acc[mt][nt] = binit;
    gemm64(Ab, Bb, l, acc);
#pragma unroll
    for (int mt = 0; mt < 4; ++mt)
#pragma unroll
      for (int nt = 0; nt < 4; ++nt)
#pragma unroll
        for (int i = 0; i < 4; ++i) {
          const int p = p0 + mt * 16 + quad * 4 + i;
          const int q = q0 + nt * 16 + rcol;
          if (!diag || (pass == 0 ? (q >= p) : (q < p)))
            Ob[(size_t)p * NL + q] = acc[mt][nt][i];
        }
  }
}

extern "C" void kernel_launch(void* const* d_in, const int* in_sizes, int n_in,
                              void* d_out, int out_size, void* d_ws, size_t ws_size,
                              hipStream_t stream) {
  const float* feats = (const float*)d_in[0];   // [B*N, D] fp32
  const float* Wu    = (const float*)d_in[1];   // [1, D, D]
  const float* bu    = (const float*)d_in[2];   // [1]
  const float* Wl    = (const float*)d_in[3];   // [1, D, D]
  const float* bl    = (const float*)d_in[4];   // [1]
  float* out = (float*)d_out;                   // [B, N, N] fp32

  char* ws = (char*)d_ws;
  short* Xf  = (short*)(ws);                                   // 8 MB (frag-tiled)
  short* YU  = (short*)(ws + (size_t)8 * 1024 * 1024);         // 8 MB
  short* YL  = (short*)(ws + (size_t)16 * 1024 * 1024);        // 8 MB
  short* WTu = (short*)(ws + (size_t)24 * 1024 * 1024);        // 128 KB
  short* WTl = (short*)(ws + (size_t)24 * 1024 * 1024 + DD * DD * 2);

  // Prep: 524288 X chunks + 16384 W chunks, one thread each.
  k_prep<<<(BL * NL * 32 + 16384) / 256, 256, 0, stream>>>(feats, Wu, Wl, Xf, WTu, WTl);

  // Stage 1: YU = Xb*Wu, YL = Xb*Wl (frag-tiled bf16 out). 512 blocks.
  k_stage1<<<dim3(BL * NL / 64, 2), 256, 0, stream>>>(Xf, WTu, WTl, YU, YL);

  // Stage 2: 1024 blocks, barrier-free register GEMM.
  k_stage2<<<dim3(64, BL), 256, 0, stream>>>(Xf, YU, YL, bu, bl, out);
}

// Round 6
// 138.434 us; speedup vs baseline: 1.3648x; 1.3648x over previous
//
#include <hip/hip_runtime.h>

// Problem constants (fixed by the reference): B=16 lists, N=1024, D=256.
#define BL 16
#define NL 1024
#define DD 256

typedef short bf16x8 __attribute__((ext_vector_type(8)));
typedef float f32x4 __attribute__((ext_vector_type(4)));

static __device__ __forceinline__ short f32_to_bf16(float f) {
  union { float f; unsigned u; } v; v.f = f;
  unsigned r = (v.u + 0x7FFFu + ((v.u >> 16) & 1u)) >> 16;  // RNE
  return (short)r;
}

// FRAGMENT-TILED LAYOUT (all bf16 operands, rows x 256 k):
//   off(row,k) = (row>>4)*4096 + (k>>5)*512 + (((k>>3)&3)*16 + (row&15))*8 + (k&7)
// A wave's 16x32 MFMA fragment is 64 lanes x 16B contiguous (lane l at +l*8
// shorts): one coalesced global_load_dwordx4 / conflict-free ds_read_b128.

// Load 4 fragments (4 row-strips of a 64-row tile) at panel p (global).
static __device__ __forceinline__ void load4(const short* __restrict__ base,
                                             int p, int l, bf16x8 f[4]) {
#pragma unroll
  for (int i = 0; i < 4; ++i)
    f[i] = *(const bf16x8*)(base + i * 4096 + p * 512 + l * 8);
}

// 64x64x256 register GEMM, A+B global frag-tiled, 2-deep pipeline, no barriers.
static __device__ __forceinline__ void gemm64(const short* __restrict__ Ab,
                                              const short* __restrict__ Bb,
                                              int l, f32x4 acc[4][4]) {
  bf16x8 a[2][4], b[2][4];
  load4(Ab, 0, l, a[0]);
  load4(Bb, 0, l, b[0]);
#pragma unroll
  for (int p = 0; p < 8; ++p) {
    if (p + 1 < 8) {
      load4(Ab, p + 1, l, a[(p + 1) & 1]);
      load4(Bb, p + 1, l, b[(p + 1) & 1]);
    }
#pragma unroll
    for (int mt = 0; mt < 4; ++mt)
#pragma unroll
      for (int nt = 0; nt < 4; ++nt)
        acc[mt][nt] = __builtin_amdgcn_mfma_f32_16x16x32_bf16(
            a[p & 1][mt], b[p & 1][nt], acc[mt][nt], 0, 0, 0);
  }
}

// 64x64x256 GEMM, A from LDS (frag-tiled), B global, B pipelined, no barriers.
static __device__ __forceinline__ void gemm64_lds(const short* As,
                                                  const short* __restrict__ Bb,
                                                  int l, f32x4 acc[4][4]) {
  bf16x8 b[2][4];
  load4(Bb, 0, l, b[0]);
#pragma unroll
  for (int p = 0; p < 8; ++p) {
    if (p + 1 < 8) load4(Bb, p + 1, l, b[(p + 1) & 1]);
    bf16x8 a[4];
#pragma unroll
    for (int mt = 0; mt < 4; ++mt)
      a[mt] = *(const bf16x8*)(As + mt * 4096 + p * 512 + l * 8);
#pragma unroll
    for (int mt = 0; mt < 4; ++mt)
#pragma unroll
      for (int nt = 0; nt < 4; ++nt)
        acc[mt][nt] = __builtin_amdgcn_mfma_f32_16x16x32_bf16(
            a[mt], b[p & 1][nt], acc[mt][nt], 0, 0, 0);
  }
}

// ---- Kernel 1: prep. X fp32->bf16 frag-tiled; W -> transposed frag-tiled.
__global__ __launch_bounds__(256) void k_prep(const float* __restrict__ X,
                                              const float* __restrict__ Wu,
                                              const float* __restrict__ Wl,
                                              short* __restrict__ Xf,
                                              short* __restrict__ WTu,
                                              short* __restrict__ WTl) {
  const int tid = blockIdx.x * 256 + threadIdx.x;
  if (tid < BL * NL * 32) {             // 524288 X chunks of 16B
    const int strip = tid >> 9, rest = tid & 511;
    const int p = rest >> 6, l = rest & 63;
    const int row = strip * 16 + (l & 15), k0 = p * 32 + (l >> 4) * 8;
    const float4* src = (const float4*)(X + (size_t)row * DD + k0);
    const float4 v0 = src[0], v1 = src[1];
    short o[8] = {f32_to_bf16(v0.x), f32_to_bf16(v0.y), f32_to_bf16(v0.z), f32_to_bf16(v0.w),
                  f32_to_bf16(v1.x), f32_to_bf16(v1.y), f32_to_bf16(v1.z), f32_to_bf16(v1.w)};
    *(bf16x8*)(Xf + (size_t)strip * 4096 + p * 512 + l * 8) = *(bf16x8*)o;
  } else {                              // 16384 W chunks (2 matrices)
    const int g = tid - BL * NL * 32;
    const int z = g >> 13, rest = g & 8191;
    const int strip = rest >> 9, rest2 = rest & 511;
    const int p = rest2 >> 6, l = rest2 & 63;
    const int e = strip * 16 + (l & 15), d0 = p * 32 + (l >> 4) * 8;
    const float* W = z ? Wl : Wu;
    short* WT = z ? WTl : WTu;
    short o[8];
#pragma unroll
    for (int j = 0; j < 8; ++j) o[j] = f32_to_bf16(W[(size_t)(d0 + j) * DD + e]);
    *(bf16x8*)(WT + (size_t)strip * 4096 + p * 512 + l * 8) = *(bf16x8*)o;
  }
}

// ---- Kernel 2: fused. One block per (list, p-tile of 64). 8 waves.
// Phase 1: Y_p = X_p * W (U and L) -> LDS, frag-tiled. One barrier.
// Phase 2: each wave streams 2 q-tiles of 64: adj = Ysel_p . X_q^T + bias.
//          A from LDS, B from global; no barriers; diagonal q-tile dual-pass.
__global__ __launch_bounds__(512, 2) void k_fused(const short* __restrict__ Xf,
                                                  const short* __restrict__ WTu,
                                                  const short* __restrict__ WTl,
                                                  const float* __restrict__ bu_p,
                                                  const float* __restrict__ bl_p,
                                                  float* __restrict__ out) {
  __shared__ short Ysh[2][64 * DD];     // [U/L][64 rows x 256 e] frag-tiled, 64 KB
  const int w = threadIdx.x >> 6, l = threadIdx.x & 63;
  const int quad = l >> 4, rcol = l & 15;
  const int pt = blockIdx.x & 15, b = blockIdx.x >> 4;
  const size_t loff = (size_t)b * NL * DD;

  // ---- Phase 1: wave w computes Y[mat= w>>2][rows 0..63][cols cg*64..+64).
  {
    const int mat = w >> 2, cg = w & 3;
    const short* Ab = Xf + loff + (size_t)pt * 64 * DD;   // frag-tiled strip base
    const short* Bb = (mat ? WTl : WTu) + (size_t)cg * 4 * 4096;
    f32x4 acc[4][4] = {};
    gemm64(Ab, Bb, l, acc);
    short* Yl = &Ysh[mat][0];
#pragma unroll
    for (int mt = 0; mt < 4; ++mt)
#pragma unroll
      for (int nt = 0; nt < 4; ++nt)
#pragma unroll
        for (int i = 0; i < 4; ++i) {
          const int e = cg * 64 + nt * 16 + rcol;
          const int rl = quad * 4 + i;  // row & 15 (strip = mt)
          Yl[mt * 4096 + (e >> 5) * 512 + (((e >> 3) & 3) * 16 + rl) * 8 + (e & 7)] =
              f32_to_bf16(acc[mt][nt][i]);
        }
  }
  __syncthreads();

  // ---- Phase 2: wave w handles q-tiles {2w, 2w+1}.
  const float bu = bu_p[0], bl = bl_p[0];
  float* Ob = out + (size_t)b * NL * NL;
  const int p0 = pt * 64;
  for (int j = 0; j < 2; ++j) {
    const int qt = w * 2 + j;
    const int q0 = qt * 64;
    const bool diag = (qt == pt);
    const int npass = diag ? 2 : 1;
    const short* Bb = Xf + loff + (size_t)qt * 64 * DD;
    for (int pass = 0; pass < npass; ++pass) {
      const bool useU = diag ? (pass == 0) : (qt > pt);
      const float bias = useU ? bu : bl;
      const f32x4 binit = {bias, bias, bias, bias};
      f32x4 acc[4][4];
#pragma unroll
      for (int mt = 0; mt < 4; ++mt)
#pragma unroll
        for (int nt = 0; nt < 4; ++nt) acc[mt][nt] = binit;
      gemm64_lds(&Ysh[useU ? 0 : 1][0], Bb, l, acc);
#pragma unroll
      for (int mt = 0; mt < 4; ++mt)
#pragma unroll
        for (int nt = 0; nt < 4; ++nt)
#pragma unroll
          for (int i = 0; i < 4; ++i) {
            const int p = p0 + mt * 16 + quad * 4 + i;
            const int q = q0 + nt * 16 + rcol;
            if (!diag || (pass == 0 ? (q >= p) : (q < p)))
              Ob[(size_t)p * NL + q] = acc[mt][nt][i];
          }
    }
  }
}

extern "C" void kernel_launch(void* const* d_in, const int* in_sizes, int n_in,
                              void* d_out, int out_size, void* d_ws, size_t ws_size,
                              hipStream_t stream) {
  const float* feats = (const float*)d_in[0];   // [B*N, D] fp32
  const float* Wu    = (const float*)d_in[1];   // [1, D, D]
  const float* bu    = (const float*)d_in[2];   // [1]
  const float* Wl    = (const float*)d_in[3];   // [1, D, D]
  const float* bl    = (const float*)d_in[4];   // [1]
  float* out = (float*)d_out;                   // [B, N, N] fp32

  char* ws = (char*)d_ws;
  short* Xf  = (short*)(ws);                                   // 8 MB frag-tiled
  short* WTu = (short*)(ws + (size_t)8 * 1024 * 1024);         // 128 KB
  short* WTl = (short*)(ws + (size_t)8 * 1024 * 1024 + DD * DD * 2);

  // Prep: 524288 X chunks + 16384 W chunks, one thread each.
  k_prep<<<(BL * NL * 32 + 16384) / 256, 256, 0, stream>>>(feats, Wu, Wl, Xf, WTu, WTl);

  // Fused stage1+stage2: 256 blocks (1/CU), 512 threads.
  k_fused<<<BL * 16, 512, 0, stream>>>(Xf, WTu, WTl, bu, bl, out);
}